// Round 1
// baseline (1044.424 us; speedup 1.0000x reference)
//
#include <hip/hip_runtime.h>
#include <math.h>

#define BB   2
#define CC   256
#define HSZ  64
#define WSZ  64
#define NQQ  4096
#define NHH  8
#define NPP  8
#define DHH  32
#define FFND 256
#define MT   (BB*NQQ)   // 8192 rows

// ---------------- fuse: softmax-weighted channel fusion + NCHW -> [B,HW,C] ----------------
__global__ void fuse_kernel(const float* __restrict__ f0, const float* __restrict__ f1,
                            const float* __restrict__ fl, float* __restrict__ fused) {
    int idx = blockIdx.x * 256 + threadIdx.x;      // over B*NQ*C
    int c = idx % CC;
    int q = (idx / CC) % NQQ;
    int b = idx / (CC * NQQ);
    float l0 = fl[c], l1 = fl[CC + c];
    float m  = fmaxf(l0, l1);
    float e0 = expf(l0 - m), e1 = expf(l1 - m);
    float inv = 1.0f / (e0 + e1);
    float v0 = f0[(b * CC + c) * NQQ + q];
    float v1 = f1[(b * CC + c) * NQQ + q];
    fused[idx] = (v0 * e0 + v1 * e1) * inv;
}

// ---------------- sine positional embedding [NQ, C] ----------------
__global__ void pos_kernel(float* __restrict__ pos) {
    int idx = blockIdx.x * 256 + threadIdx.x;      // over NQ*C
    int c = idx % CC;
    int q = idx / CC;
    int h = q / WSZ, w = q % WSZ;
    const float scale = 6.28318530717958647692f;
    float coord;
    int cf = c;
    if (c < 128) {
        coord = (float)(h + 1) / (64.0f + 1e-6f) * scale;
    } else {
        coord = (float)(w + 1) / (64.0f + 1e-6f) * scale;
        cf = c - 128;
    }
    int k = cf >> 1;
    float dimt = powf(10000.0f, (float)k / 64.0f);
    float v = coord / dimt;
    pos[idx] = (cf & 1) ? cosf(v) : sinf(v);
}

// ---------------- reference points: sigmoid(qe @ ref_w + ref_b), [NQ,2] ----------------
__global__ void refpts_kernel(const float* __restrict__ qemb, const float* __restrict__ rw,
                              const float* __restrict__ rb, float* __restrict__ refp) {
    int q = blockIdx.x * 64 + threadIdx.x;
    if (q >= NQQ) return;
    float a0 = rb[0], a1 = rb[1];
    const float* row = qemb + (size_t)q * 2 * CC;
    for (int k = 0; k < CC; k++) {
        float x = row[k];
        a0 += x * rw[k * 2 + 0];
        a1 += x * rw[k * 2 + 1];
    }
    refp[q * 2 + 0] = 1.0f / (1.0f + expf(-a0));
    refp[q * 2 + 1] = 1.0f / (1.0f + expf(-a1));
}

// ---------------- tgt init: query_embed[:, C:] broadcast over B ----------------
__global__ void tgt_init_kernel(const float* __restrict__ qemb, float* __restrict__ tgt) {
    int idx = blockIdx.x * 256 + threadIdx.x;      // over B*NQ*C
    int c = idx % CC;
    int q = (idx / CC) % NQQ;
    tgt[idx] = qemb[(size_t)q * 2 * CC + CC + c];
}

// ---------------- layernorm (one row per block of 256 threads), optional add ----------------
// addMode: 0 = none, 1 = + query_embed[:, :C] (stride 2C, b-broadcast)
__global__ void ln_kernel(const float* __restrict__ x, const float* __restrict__ g,
                          const float* __restrict__ bt, const float* __restrict__ addp,
                          int addMode, float* __restrict__ out) {
    int row = blockIdx.x;            // b*NQ + q
    int c = threadIdx.x;
    int q = row % NQQ;
    __shared__ float red[256];
    float v = x[(size_t)row * CC + c];
    red[c] = v; __syncthreads();
    for (int s = 128; s > 0; s >>= 1) { if (c < s) red[c] += red[c + s]; __syncthreads(); }
    float mean = red[0] * (1.0f / CC);
    __syncthreads();
    float d = v - mean;
    red[c] = d * d; __syncthreads();
    for (int s = 128; s > 0; s >>= 1) { if (c < s) red[c] += red[c + s]; __syncthreads(); }
    float var = red[0] * (1.0f / CC);
    float r = (v - mean) * rsqrtf(var + 1e-5f) * g[c] + bt[c];
    if (addMode == 1) r += addp[(size_t)q * 2 * CC + c];
    out[(size_t)row * CC + c] = r;
}

// ---------------- t2q = tgt + pos (pos broadcast over b) ----------------
__global__ void addpos_kernel(const float* __restrict__ tgt, const float* __restrict__ pos,
                              float* __restrict__ out) {
    int idx = blockIdx.x * 256 + threadIdx.x;
    int qc = idx % (NQQ * CC);
    out[idx] = tgt[idx] + pos[qc];
}

// ---------------- tiled f32 GEMM: C[M,N] = A[M,K] @ W[K,N] + bias ----------------
// mode: 0 store, 1 relu-store, 2 accumulate, 3 relu-then-accumulate
#define Bb 64
#define BKK 16
__global__ __launch_bounds__(256) void gemm_kernel(const float* __restrict__ A,
                                                   const float* __restrict__ W,
                                                   const float* __restrict__ bias,
                                                   float* __restrict__ Cmat,
                                                   int M, int N, int K, int mode) {
    __shared__ float As[BKK][Bb + 1];
    __shared__ float Wsh[BKK][Bb];
    int t = threadIdx.x;
    int tx = t % 16, ty = t / 16;
    int m0 = blockIdx.x * Bb, n0 = blockIdx.y * Bb;
    float acc[4][4] = {};
    for (int k0 = 0; k0 < K; k0 += BKK) {
        #pragma unroll
        for (int i = 0; i < 4; i++) {
            int lin = t + i * 256;
            int m = lin >> 4;
            int k = lin & 15;
            As[k][m] = A[(size_t)(m0 + m) * K + k0 + k];
        }
        #pragma unroll
        for (int i = 0; i < 4; i++) {
            int lin = t + i * 256;
            int k = lin >> 6;
            int n = lin & 63;
            Wsh[k][n] = W[(size_t)(k0 + k) * N + n0 + n];
        }
        __syncthreads();
        #pragma unroll
        for (int k = 0; k < BKK; k++) {
            float a[4], bv[4];
            #pragma unroll
            for (int i = 0; i < 4; i++) a[i] = As[k][ty * 4 + i];
            #pragma unroll
            for (int j = 0; j < 4; j++) bv[j] = Wsh[k][tx * 4 + j];
            #pragma unroll
            for (int i = 0; i < 4; i++)
                #pragma unroll
                for (int j = 0; j < 4; j++)
                    acc[i][j] += a[i] * bv[j];
        }
        __syncthreads();
    }
    #pragma unroll
    for (int i = 0; i < 4; i++) {
        int m = m0 + ty * 4 + i;
        #pragma unroll
        for (int j = 0; j < 4; j++) {
            int n = n0 + tx * 4 + j;
            float v = acc[i][j] + bias[n];
            if (mode == 0) {
                Cmat[(size_t)m * N + n] = v;
            } else if (mode == 1) {
                Cmat[(size_t)m * N + n] = fmaxf(v, 0.0f);
            } else if (mode == 2) {
                Cmat[(size_t)m * N + n] += v;
            } else {
                Cmat[(size_t)m * N + n] += fmaxf(v, 0.0f);
            }
        }
    }
}

// ---------------- softmax over NP=8 per (b,q,h), in place ----------------
__global__ void awsm_kernel(float* __restrict__ aw) {
    int g = blockIdx.x * 256 + threadIdx.x;        // B*NQ*NH
    float* p = aw + (size_t)g * NPP;
    float mx = p[0];
    #pragma unroll
    for (int i = 1; i < 8; i++) mx = fmaxf(mx, p[i]);
    float e[8], s = 0.0f;
    #pragma unroll
    for (int i = 0; i < 8; i++) { e[i] = expf(p[i] - mx); s += e[i]; }
    float inv = 1.0f / s;
    #pragma unroll
    for (int i = 0; i < 8; i++) p[i] = e[i] * inv;
}

// ---------------- deformable bilinear sampling + attention-weighted sum ----------------
__global__ void sample_kernel(const float* __restrict__ value, const float* __restrict__ off,
                              const float* __restrict__ aw, const float* __restrict__ refp,
                              int isSelf, float* __restrict__ samp) {
    int idx = blockIdx.x * 256 + threadIdx.x;      // B*NQ*NH*DH = 2^21
    int d = idx & (DHH - 1);
    int h = (idx >> 5) & (NHH - 1);
    int q = (idx >> 8) & (NQQ - 1);
    int b = idx >> 20;

    float rxs, rys;
    if (isSelf) {
        rxs = ((float)(q & 63) + 0.5f) * 64.0f;
        rys = ((float)(q >> 6) + 0.5f) * 64.0f;
    } else {
        rxs = refp[q * 2 + 0] * 64.0f;
        rys = refp[q * 2 + 1] * 64.0f;
    }
    const float* offp = off + ((size_t)(b * NQQ + q) * NHH + h) * NPP * 2;
    const float* awp  = aw  + ((size_t)(b * NQQ + q) * NHH + h) * NPP;
    const float* vb   = value + (size_t)b * NQQ * CC + h * DHH + d;

    auto corner = [&](int xi, int yi, float w) -> float {
        bool inb = (xi >= 0) && (xi < WSZ) && (yi >= 0) && (yi < HSZ);
        int xc = xi < 0 ? 0 : (xi > WSZ - 1 ? WSZ - 1 : xi);
        int yc = yi < 0 ? 0 : (yi > HSZ - 1 ? HSZ - 1 : yi);
        float v = vb[(yc * WSZ + xc) * CC];
        return inb ? w * v : 0.0f;
    };

    float accv = 0.0f;
    #pragma unroll
    for (int p = 0; p < NPP; p++) {
        float px = rxs + offp[p * 2 + 0] - 0.5f;
        float py = rys + offp[p * 2 + 1] - 0.5f;
        float x0f = floorf(px), y0f = floorf(py);
        float lx = px - x0f, ly = py - y0f;
        int x0 = (int)x0f, y0 = (int)y0f;
        float s = corner(x0,     y0,     (1.0f - lx) * (1.0f - ly))
                + corner(x0 + 1, y0,     lx * (1.0f - ly))
                + corner(x0,     y0 + 1, (1.0f - lx) * ly)
                + corner(x0 + 1, y0 + 1, lx * ly);
        accv += awp[p] * s;
    }
    samp[(size_t)(b * NQQ + q) * CC + h * DHH + d] = accv;
}

extern "C" void kernel_launch(void* const* d_in, const int* in_sizes, int n_in,
                              void* d_out, int out_size, void* d_ws, size_t ws_size,
                              hipStream_t stream) {
    const float* feat0 = (const float*)d_in[0];
    const float* feat1 = (const float*)d_in[1];
    const float* qemb  = (const float*)d_in[2];
    const float* ref_w = (const float*)d_in[3];
    const float* ref_b = (const float*)d_in[4];
    const float* fl    = (const float*)d_in[5];
    const float* ln1_g = (const float*)d_in[6];
    const float* ln1_b = (const float*)d_in[7];
    const float* off_w = (const float*)d_in[8];
    const float* off_b = (const float*)d_in[9];
    const float* aw_w  = (const float*)d_in[10];
    const float* aw_b  = (const float*)d_in[11];
    const float* val_w = (const float*)d_in[12];
    const float* val_b = (const float*)d_in[13];
    const float* out_w = (const float*)d_in[14];
    const float* out_b = (const float*)d_in[15];
    const float* ln2_g = (const float*)d_in[16];
    const float* ln2_b = (const float*)d_in[17];
    const float* f1_w  = (const float*)d_in[18];
    const float* f1_b  = (const float*)d_in[19];
    const float* f2_w  = (const float*)d_in[20];
    const float* f2_b  = (const float*)d_in[21];

    float* tgt = (float*)d_out;                 // [B, NQ, C] — lives in d_out
    float* ws  = (float*)d_ws;
    float* fused = ws;                          // MT*C
    float* pos   = fused + (size_t)MT * CC;     // NQ*C
    float* refp  = pos + (size_t)NQQ * CC;      // NQ*2
    float* t2q   = refp + (size_t)NQQ * 2;      // MT*C
    float* value = t2q + (size_t)MT * CC;       // MT*C
    float* offb  = value + (size_t)MT * CC;     // MT*128
    float* awb   = offb + (size_t)MT * NHH * NPP * 2;  // MT*64
    float* samp  = awb + (size_t)MT * NHH * NPP;       // MT*C
    float* hbuf  = samp + (size_t)MT * CC;             // MT*C

    fuse_kernel<<<MT * CC / 256, 256, 0, stream>>>(feat0, feat1, fl, fused);
    pos_kernel<<<NQQ * CC / 256, 256, 0, stream>>>(pos);
    refpts_kernel<<<NQQ / 64, 64, 0, stream>>>(qemb, ref_w, ref_b, refp);
    tgt_init_kernel<<<MT * CC / 256, 256, 0, stream>>>(qemb, tgt);

    for (int i = 0; i < 4; i++) {
        bool isSelf = (i >= 2);
        const float* src = isSelf ? (const float*)tgt : (const float*)fused;

        // value = src @ val_w[i] + val_b[i]
        gemm_kernel<<<dim3(MT / 64, CC / 64), 256, 0, stream>>>(
            src, val_w + (size_t)i * CC * CC, val_b + i * CC, value, MT, CC, CC, 0);

        // query tensor
        if (!isSelf)
            ln_kernel<<<MT, 256, 0, stream>>>(tgt, ln1_g + i * CC, ln1_b + i * CC, qemb, 1, t2q);
        else
            addpos_kernel<<<MT * CC / 256, 256, 0, stream>>>(tgt, pos, t2q);

        // offsets [MT,128], attention logits [MT,64]
        gemm_kernel<<<dim3(MT / 64, 128 / 64), 256, 0, stream>>>(
            t2q, off_w + (size_t)i * CC * 128, off_b + i * 128, offb, MT, 128, CC, 0);
        gemm_kernel<<<dim3(MT / 64, 64 / 64), 256, 0, stream>>>(
            t2q, aw_w + (size_t)i * CC * 64, aw_b + i * 64, awb, MT, 64, CC, 0);
        awsm_kernel<<<MT * NHH / 256, 256, 0, stream>>>(awb);

        // deformable sampling
        sample_kernel<<<MT * NHH * DHH / 256, 256, 0, stream>>>(
            value, offb, awb, refp, isSelf ? 1 : 0, samp);

        // tgt += samp @ out_w[i] + out_b[i]
        gemm_kernel<<<dim3(MT / 64, CC / 64), 256, 0, stream>>>(
            samp, out_w + (size_t)i * CC * CC, out_b + i * CC, tgt, MT, CC, CC, 2);

        // FFN: tgt += relu(relu(LN(tgt) @ f1 + b1) @ f2 + b2)
        ln_kernel<<<MT, 256, 0, stream>>>(tgt, ln2_g + i * CC, ln2_b + i * CC, nullptr, 0, t2q);
        gemm_kernel<<<dim3(MT / 64, FFND / 64), 256, 0, stream>>>(
            t2q, f1_w + (size_t)i * CC * FFND, f1_b + i * FFND, hbuf, MT, FFND, CC, 1);
        gemm_kernel<<<dim3(MT / 64, CC / 64), 256, 0, stream>>>(
            hbuf, f2_w + (size_t)i * FFND * CC, f2_b + i * CC, tgt, MT, CC, FFND, 3);
    }
}

// Round 2
// 260.545 us; speedup vs baseline: 4.0086x; 4.0086x over previous
//
#include <hip/hip_runtime.h>
#include <hip/hip_bf16.h>
#include <math.h>

#define BB   2
#define CC   256
#define HSZ  64
#define WSZ  64
#define NQQ  4096
#define NHH  8
#define NPP  8
#define DHH  32
#define FFND 256
#define MT   (BB*NQQ)   // 8192 rows

typedef __attribute__((ext_vector_type(4))) short s4v;
typedef __attribute__((ext_vector_type(4))) float f4v;

static __device__ __forceinline__ ushort f2bu(float f) {
    __hip_bfloat16 h = __float2bfloat16(f);
    return *reinterpret_cast<ushort*>(&h);
}

// ---------------- weight prep: transpose f32 [K][N] -> bf16 [N][K] (K=256 always) ----------
__global__ __launch_bounds__(256) void wprep_kernel(
        const float* __restrict__ val_w, const float* __restrict__ off_w,
        const float* __restrict__ aw_w,  const float* __restrict__ out_w,
        const float* __restrict__ f1_w,  const float* __restrict__ f2_w,
        const float* __restrict__ off_b, const float* __restrict__ aw_b,
        ushort* __restrict__ wval01, ushort* __restrict__ wvalS,
        ushort* __restrict__ woffaw, ushort* __restrict__ wout,
        ushort* __restrict__ wf1, ushort* __restrict__ wf2,
        float* __restrict__ bOA) {
    int bid = blockIdx.x;
    if (bid >= 304) {                           // bias concat for off/aw
        int layer = bid - 304;
        int t = threadIdx.x;
        if (t < 192)
            bOA[layer * 192 + t] = (t < 128) ? off_b[layer * 128 + t]
                                             : aw_b[layer * 64 + (t - 128)];
        return;
    }
    const float* src; ushort* dst; int srcStride;
    if (bid < 32) {                 // wval01: layers 0,1 stacked along N (512 rows)
        int nt = bid & 7, kt = bid >> 3;
        int layer = nt >> 2, nn = (nt & 3) * 64;
        src = val_w + (size_t)layer * 65536 + (size_t)kt * 64 * 256 + nn; srcStride = 256;
        dst = wval01 + (size_t)nt * 64 * 256 + kt * 64;
    } else if (bid < 64) {          // wvalS: layers 2,3
        int b = bid - 32; int layer = b >> 4; int kt = (b >> 2) & 3; int nt = b & 3;
        src = val_w + (size_t)(2 + layer) * 65536 + (size_t)kt * 64 * 256 + nt * 64; srcStride = 256;
        dst = wvalS + (size_t)layer * 65536 + (size_t)nt * 64 * 256 + kt * 64;
    } else if (bid < 112) {         // woffaw: [192][256] per layer (off rows 0..127, aw 128..191)
        int b = bid - 64; int layer = b / 12; int rem = b % 12; int kt = rem / 3; int nt = rem % 3;
        if (nt < 2) { src = off_w + (size_t)layer * 256 * 128 + (size_t)kt * 64 * 128 + nt * 64; srcStride = 128; }
        else        { src = aw_w  + (size_t)layer * 256 * 64  + (size_t)kt * 64 * 64;            srcStride = 64;  }
        dst = woffaw + (size_t)layer * 192 * 256 + (size_t)nt * 64 * 256 + kt * 64;
    } else {                        // wout / wf1 / wf2
        int b = bid - 112; int fam = b >> 6; int bb = b & 63;
        int layer = bb >> 4; int kt = (bb >> 2) & 3; int nt = bb & 3;
        const float* s0 = (fam == 0) ? out_w : ((fam == 1) ? f1_w : f2_w);
        ushort* d0      = (fam == 0) ? wout  : ((fam == 1) ? wf1  : wf2);
        src = s0 + (size_t)layer * 65536 + (size_t)kt * 64 * 256 + nt * 64; srcStride = 256;
        dst = d0 + (size_t)layer * 65536 + (size_t)nt * 64 * 256 + kt * 64;
    }
    __shared__ float tl[64][65];
    int t = threadIdx.x; int r = t >> 6, c = t & 63;
    #pragma unroll
    for (int rr = 0; rr < 64; rr += 4)
        tl[rr + r][c] = src[(size_t)(rr + r) * srcStride + c];
    __syncthreads();
    #pragma unroll
    for (int rr = 0; rr < 64; rr += 4)
        dst[(size_t)(rr + r) * 256 + c] = f2bu(tl[c][rr + r]);
}

// ---------------- fuse: softmax channel fusion + NCHW -> [B,HW,C], bf16 out --------------
__global__ __launch_bounds__(256) void fuse_kernel(const float* __restrict__ f0,
        const float* __restrict__ f1, const float* __restrict__ fl,
        ushort* __restrict__ fused) {
    int bid = blockIdx.x;
    int b = bid >> 8;
    int c0 = ((bid >> 6) & 3) * 64;
    int q0 = (bid & 63) * 64;
    __shared__ float tl[64][65];
    int t = threadIdx.x;
    int r = t >> 6, c = t & 63;
    #pragma unroll
    for (int rr = 0; rr < 64; rr += 4) {
        int ch = c0 + rr + r;
        float l0 = fl[ch], l1 = fl[CC + ch];
        float m = fmaxf(l0, l1);
        float e0 = __expf(l0 - m), e1 = __expf(l1 - m);
        float inv = 1.0f / (e0 + e1);
        size_t o = ((size_t)b * CC + ch) * NQQ + q0 + c;
        tl[rr + r][c] = (f0[o] * e0 + f1[o] * e1) * inv;
    }
    __syncthreads();
    #pragma unroll
    for (int rr = 0; rr < 64; rr += 4)
        fused[((size_t)(b * NQQ + q0 + rr + r)) * CC + c0 + c] = f2bu(tl[c][rr + r]);
}

// ---------------- sine positional embedding [NQ, C] f32 ----------------
__global__ void pos_kernel(float* __restrict__ pos) {
    int idx = blockIdx.x * 256 + threadIdx.x;
    int c = idx % CC;
    int q = idx / CC;
    int h = q / WSZ, w = q % WSZ;
    const float scale = 6.28318530717958647692f;
    float coord;
    int cf = c;
    if (c < 128) coord = (float)(h + 1) / (64.0f + 1e-6f) * scale;
    else { coord = (float)(w + 1) / (64.0f + 1e-6f) * scale; cf = c - 128; }
    int k = cf >> 1;
    float dimt = powf(10000.0f, (float)k / 64.0f);
    float v = coord / dimt;
    pos[idx] = (cf & 1) ? cosf(v) : sinf(v);
}

// ---------------- reference points: sigmoid(qe @ ref_w + ref_b), wave per row ------------
__global__ __launch_bounds__(256) void refpts_kernel(const float* __restrict__ qemb,
        const float* __restrict__ rw, const float* __restrict__ rb, float* __restrict__ refp) {
    int row = blockIdx.x * 4 + (threadIdx.x >> 6);
    int l = threadIdx.x & 63;
    float4 v = *(const float4*)(qemb + (size_t)row * 512 + l * 4);
    float a0 = v.x * rw[(l * 4 + 0) * 2] + v.y * rw[(l * 4 + 1) * 2]
             + v.z * rw[(l * 4 + 2) * 2] + v.w * rw[(l * 4 + 3) * 2];
    float a1 = v.x * rw[(l * 4 + 0) * 2 + 1] + v.y * rw[(l * 4 + 1) * 2 + 1]
             + v.z * rw[(l * 4 + 2) * 2 + 1] + v.w * rw[(l * 4 + 3) * 2 + 1];
    #pragma unroll
    for (int o = 32; o > 0; o >>= 1) { a0 += __shfl_xor(a0, o); a1 += __shfl_xor(a1, o); }
    if (l == 0) {
        refp[row * 2 + 0] = 1.0f / (1.0f + __expf(-(a0 + rb[0])));
        refp[row * 2 + 1] = 1.0f / (1.0f + __expf(-(a1 + rb[1])));
    }
}

// ---------------- tgt init: query_embed[:, C:] broadcast over B, float4 ------------------
__global__ void tgt_init_kernel(const float* __restrict__ qemb, float* __restrict__ tgt) {
    int idx = blockIdx.x * 256 + threadIdx.x;   // MT*C/4
    int c4 = idx & 63;
    int q = (idx >> 6) & (NQQ - 1);
    *(float4*)(tgt + (size_t)idx * 4) = *(const float4*)(qemb + (size_t)q * 512 + 256 + c4 * 4);
}

// ---------------- layernorm: wave per row, bf16 out, optional +qe ------------------------
__global__ __launch_bounds__(256) void ln_kernel(const float* __restrict__ x,
        const float* __restrict__ g, const float* __restrict__ bt,
        const float* __restrict__ addp, int addMode, ushort* __restrict__ out) {
    int row = blockIdx.x * 4 + (threadIdx.x >> 6);
    int l = threadIdx.x & 63;
    int q = row & (NQQ - 1);
    float4 v = *(const float4*)(x + (size_t)row * CC + l * 4);
    float s = v.x + v.y + v.z + v.w;
    #pragma unroll
    for (int o = 32; o > 0; o >>= 1) s += __shfl_xor(s, o);
    float mean = s * (1.0f / CC);
    float dx = v.x - mean, dy = v.y - mean, dz = v.z - mean, dw = v.w - mean;
    float s2 = dx * dx + dy * dy + dz * dz + dw * dw;
    #pragma unroll
    for (int o = 32; o > 0; o >>= 1) s2 += __shfl_xor(s2, o);
    float rstd = rsqrtf(s2 * (1.0f / CC) + 1e-5f);
    float4 gv = *(const float4*)(g + l * 4);
    float4 bv = *(const float4*)(bt + l * 4);
    float o0 = dx * rstd * gv.x + bv.x;
    float o1 = dy * rstd * gv.y + bv.y;
    float o2 = dz * rstd * gv.z + bv.z;
    float o3 = dw * rstd * gv.w + bv.w;
    if (addMode) {
        float4 av = *(const float4*)(addp + (size_t)q * 512 + l * 4);
        o0 += av.x; o1 += av.y; o2 += av.z; o3 += av.w;
    }
    ushort4 pk; pk.x = f2bu(o0); pk.y = f2bu(o1); pk.z = f2bu(o2); pk.w = f2bu(o3);
    *(ushort4*)(out + (size_t)row * CC + l * 4) = pk;
}

// ---------------- addpos: t2q_bf = bf16(tgt+pos), tgt_bf = bf16(tgt) ---------------------
__global__ void addpos_kernel(const float* __restrict__ tgt, const float* __restrict__ pos,
                              ushort* __restrict__ t2q_bf, ushort* __restrict__ tgt_bf) {
    int idx = blockIdx.x * 256 + threadIdx.x;   // MT*C/4
    int qc = idx & (NQQ * 64 - 1);
    float4 tv = *(const float4*)(tgt + (size_t)idx * 4);
    float4 pv = *(const float4*)(pos + (size_t)qc * 4);
    ushort4 a, bq;
    a.x = f2bu(tv.x + pv.x); a.y = f2bu(tv.y + pv.y);
    a.z = f2bu(tv.z + pv.z); a.w = f2bu(tv.w + pv.w);
    bq.x = f2bu(tv.x); bq.y = f2bu(tv.y); bq.z = f2bu(tv.z); bq.w = f2bu(tv.w);
    *(ushort4*)(t2q_bf + (size_t)idx * 4) = a;
    *(ushort4*)(tgt_bf + (size_t)idx * 4) = bq;
}

// ---------------- bf16 MFMA GEMM: C[M,N] = A[M,256] @ Bt[N,256]^T + bias -----------------
// MODE 0: f32 store   1: bf16 relu store   2: f32 accumulate   3: relu f32 accumulate
template<int MODE>
__global__ __launch_bounds__(256) void mgemm(const ushort* __restrict__ A,
                                             const ushort* __restrict__ Bt,
                                             const float* __restrict__ bias,
                                             float* __restrict__ Cf,
                                             ushort* __restrict__ Cb,
                                             int N) {
    constexpr int LDT = 72;                   // 144B row stride: 16B-aligned, ~2-way banks
    __shared__ ushort As[64 * LDT];
    __shared__ ushort Bs[64 * LDT];
    const int t = threadIdx.x;
    const int l = t & 63;
    const int w = t >> 6;
    const int wm = w >> 1, wn = w & 1;
    const int m0 = blockIdx.x * 64, n0 = blockIdx.y * 64;
    const int srow = t >> 3;                  // 0..31
    const int sk = (t & 7) * 8;               // 0..56
    const ushort* Ab = A + (size_t)(m0 + srow) * 256 + sk;
    const ushort* Bb = Bt + (size_t)(n0 + srow) * 256 + sk;
    f4v acc[2][2] = {};
    const int fr = l & 15;
    const int fk = (l >> 4) * 4;
    for (int k0 = 0; k0 < 256; k0 += 64) {
        int4 va0 = *(const int4*)(Ab + k0);
        int4 va1 = *(const int4*)(Ab + 32 * 256 + k0);
        int4 vb0 = *(const int4*)(Bb + k0);
        int4 vb1 = *(const int4*)(Bb + 32 * 256 + k0);
        __syncthreads();
        *(int4*)(As + srow * LDT + sk) = va0;
        *(int4*)(As + (srow + 32) * LDT + sk) = va1;
        *(int4*)(Bs + srow * LDT + sk) = vb0;
        *(int4*)(Bs + (srow + 32) * LDT + sk) = vb1;
        __syncthreads();
        #pragma unroll
        for (int kf = 0; kf < 4; kf++) {
            const int kk = kf * 16 + fk;
            s4v a0 = *(const s4v*)(As + (wm * 32 + fr) * LDT + kk);
            s4v a1 = *(const s4v*)(As + (wm * 32 + 16 + fr) * LDT + kk);
            s4v b0 = *(const s4v*)(Bs + (wn * 32 + fr) * LDT + kk);
            s4v b1 = *(const s4v*)(Bs + (wn * 32 + 16 + fr) * LDT + kk);
            acc[0][0] = __builtin_amdgcn_mfma_f32_16x16x16bf16_1k(a0, b0, acc[0][0], 0, 0, 0);
            acc[0][1] = __builtin_amdgcn_mfma_f32_16x16x16bf16_1k(a0, b1, acc[0][1], 0, 0, 0);
            acc[1][0] = __builtin_amdgcn_mfma_f32_16x16x16bf16_1k(a1, b0, acc[1][0], 0, 0, 0);
            acc[1][1] = __builtin_amdgcn_mfma_f32_16x16x16bf16_1k(a1, b1, acc[1][1], 0, 0, 0);
        }
    }
    const int rb = (l >> 4) * 4;
    #pragma unroll
    for (int i = 0; i < 2; i++)
        #pragma unroll
        for (int j = 0; j < 2; j++) {
            int gm = m0 + wm * 32 + i * 16 + rb;
            int gn = n0 + wn * 32 + j * 16 + fr;
            float bz = bias[gn];
            #pragma unroll
            for (int r = 0; r < 4; r++) {
                float v = acc[i][j][r] + bz;
                size_t off = (size_t)(gm + r) * N + gn;
                if (MODE == 0)      Cf[off] = v;
                else if (MODE == 1) Cb[off] = f2bu(fmaxf(v, 0.0f));
                else if (MODE == 2) Cf[off] += v;
                else                Cf[off] += fmaxf(v, 0.0f);
            }
        }
}

// ---------------- deformable sampling: softmax(NP) fused, float4 over d ------------------
__global__ __launch_bounds__(256) void sample_kernel(const float* __restrict__ value, int vstride,
        const float* __restrict__ offaw, const float* __restrict__ refp,
        int isSelf, ushort* __restrict__ samp) {
    int idx = blockIdx.x * 256 + threadIdx.x;   // MT*NH*8
    int d4 = idx & 7;
    int h  = (idx >> 3) & 7;
    int q  = (idx >> 6) & (NQQ - 1);
    int b  = idx >> 18;
    int row = b * NQQ + q;
    float rxs, rys;
    if (isSelf) { rxs = (float)(q & 63) * 64.0f + 32.0f; rys = (float)(q >> 6) * 64.0f + 32.0f; }
    else        { rxs = refp[q * 2] * 64.0f;             rys = refp[q * 2 + 1] * 64.0f; }
    const float* oa = offaw + (size_t)row * 192;
    float lg[8];
    #pragma unroll
    for (int p = 0; p < 8; p++) lg[p] = oa[128 + h * 8 + p];
    float mx = lg[0];
    #pragma unroll
    for (int p = 1; p < 8; p++) mx = fmaxf(mx, lg[p]);
    float wg[8], wsum = 0.0f;
    #pragma unroll
    for (int p = 0; p < 8; p++) { wg[p] = __expf(lg[p] - mx); wsum += wg[p]; }
    float inv = 1.0f / wsum;
    const float* offp = oa + h * 16;
    const float* vb = value + (size_t)b * NQQ * vstride + h * 32 + d4 * 4;
    float ax = 0, ay = 0, az = 0, aw2 = 0;
    #pragma unroll
    for (int p = 0; p < 8; p++) {
        float px = rxs + offp[p * 2]     - 0.5f;
        float py = rys + offp[p * 2 + 1] - 0.5f;
        float x0f = floorf(px), y0f = floorf(py);
        float lx = px - x0f, ly = py - y0f;
        int x0 = (int)x0f, y0 = (int)y0f;
        float wgt = wg[p] * inv;
        float w00 = (1 - lx) * (1 - ly) * wgt, w10 = lx * (1 - ly) * wgt;
        float w01 = (1 - lx) * ly * wgt,       w11 = lx * ly * wgt;
        #pragma unroll
        for (int cn = 0; cn < 4; cn++) {
            int xi = x0 + (cn & 1), yi = y0 + (cn >> 1);
            float wc = (cn == 0) ? w00 : (cn == 1) ? w10 : (cn == 2) ? w01 : w11;
            if (xi >= 0 && xi < WSZ && yi >= 0 && yi < HSZ) {
                float4 cv = *(const float4*)(vb + (size_t)(yi * WSZ + xi) * vstride);
                ax += wc * cv.x; ay += wc * cv.y; az += wc * cv.z; aw2 += wc * cv.w;
            }
        }
    }
    ushort4 pk; pk.x = f2bu(ax); pk.y = f2bu(ay); pk.z = f2bu(az); pk.w = f2bu(aw2);
    *(ushort4*)(samp + (size_t)row * CC + h * 32 + d4 * 4) = pk;
}

extern "C" void kernel_launch(void* const* d_in, const int* in_sizes, int n_in,
                              void* d_out, int out_size, void* d_ws, size_t ws_size,
                              hipStream_t stream) {
    const float* feat0 = (const float*)d_in[0];
    const float* feat1 = (const float*)d_in[1];
    const float* qemb  = (const float*)d_in[2];
    const float* ref_w = (const float*)d_in[3];
    const float* ref_b = (const float*)d_in[4];
    const float* fl    = (const float*)d_in[5];
    const float* ln1_g = (const float*)d_in[6];
    const float* ln1_b = (const float*)d_in[7];
    const float* off_w = (const float*)d_in[8];
    const float* off_b = (const float*)d_in[9];
    const float* aw_w  = (const float*)d_in[10];
    const float* aw_b  = (const float*)d_in[11];
    const float* val_w = (const float*)d_in[12];
    const float* val_b = (const float*)d_in[13];
    const float* out_w = (const float*)d_in[14];
    const float* out_b = (const float*)d_in[15];
    const float* ln2_g = (const float*)d_in[16];
    const float* ln2_b = (const float*)d_in[17];
    const float* f1_w  = (const float*)d_in[18];
    const float* f1_b  = (const float*)d_in[19];
    const float* f2_w  = (const float*)d_in[20];
    const float* f2_b  = (const float*)d_in[21];

    float* tgt = (float*)d_out;                              // [B,NQ,C]
    float* ws = (float*)d_ws;
    float* pos     = ws;                                     // 1,048,576 f32
    float* refp    = pos + 1048576;                          // 8,192
    float* value01 = refp + 8192;                            // MT*512 (self value aliases)
    float* offaw   = value01 + (size_t)MT * 512;             // MT*192
    float* bOA     = offaw + (size_t)MT * 192;               // 768
    ushort* wval01 = (ushort*)(bOA + 768);                   // 131072
    ushort* wvalS  = wval01 + 131072;                        // 131072
    ushort* woffaw = wvalS + 131072;                         // 196608
    ushort* wout   = woffaw + 196608;                        // 262144
    ushort* wf1    = wout + 262144;                          // 262144
    ushort* wf2    = wf1 + 262144;                           // 262144
    ushort* t2q_bf = wf2 + 262144;                           // MT*C
    ushort* samp_bf= t2q_bf + (size_t)MT * CC;               // MT*C
    ushort* hbuf_bf= samp_bf + (size_t)MT * CC;              // MT*C
    ushort* tgt_bf = hbuf_bf + (size_t)MT * CC;              // MT*C (fused_bf aliases)
    ushort* fused_bf = tgt_bf;

    wprep_kernel<<<308, 256, 0, stream>>>(val_w, off_w, aw_w, out_w, f1_w, f2_w,
                                          off_b, aw_b,
                                          wval01, wvalS, woffaw, wout, wf1, wf2, bOA);
    fuse_kernel<<<512, 256, 0, stream>>>(feat0, feat1, fl, fused_bf);
    pos_kernel<<<NQQ * CC / 256, 256, 0, stream>>>(pos);
    refpts_kernel<<<NQQ / 4, 256, 0, stream>>>(qemb, ref_w, ref_b, refp);
    tgt_init_kernel<<<MT * CC / 4 / 256, 256, 0, stream>>>(qemb, tgt);

    // both cross-layer value projections at once: [MT,512]
    mgemm<0><<<dim3(MT / 64, 8), 256, 0, stream>>>(fused_bf, wval01, val_b, value01, nullptr, 512);

    for (int i = 0; i < 2; i++) {       // cross layers
        ln_kernel<<<MT / 4, 256, 0, stream>>>(tgt, ln1_g + i * CC, ln1_b + i * CC, qemb, 1, t2q_bf);
        mgemm<0><<<dim3(MT / 64, 3), 256, 0, stream>>>(t2q_bf, woffaw + (size_t)i * 192 * 256,
                                                       bOA + i * 192, offaw, nullptr, 192);
        sample_kernel<<<MT * NHH * 8 / 256, 256, 0, stream>>>(value01 + i * 256, 512,
                                                              offaw, refp, 0, samp_bf);
        mgemm<2><<<dim3(MT / 64, 4), 256, 0, stream>>>(samp_bf, wout + (size_t)i * 65536,
                                                       out_b + i * CC, tgt, nullptr, 256);
        ln_kernel<<<MT / 4, 256, 0, stream>>>(tgt, ln2_g + i * CC, ln2_b + i * CC, nullptr, 0, t2q_bf);
        mgemm<1><<<dim3(MT / 64, 4), 256, 0, stream>>>(t2q_bf, wf1 + (size_t)i * 65536,
                                                       f1_b + i * FFND, nullptr, hbuf_bf, 256);
        mgemm<3><<<dim3(MT / 64, 4), 256, 0, stream>>>(hbuf_bf, wf2 + (size_t)i * 65536,
                                                       f2_b + i * CC, tgt, nullptr, 256);
    }
    for (int i = 2; i < 4; i++) {       // self layers
        addpos_kernel<<<MT * CC / 4 / 256, 256, 0, stream>>>(tgt, pos, t2q_bf, tgt_bf);
        mgemm<0><<<dim3(MT / 64, 4), 256, 0, stream>>>(tgt_bf, wvalS + (size_t)(i - 2) * 65536,
                                                       val_b + i * CC, value01, nullptr, 256);
        mgemm<0><<<dim3(MT / 64, 3), 256, 0, stream>>>(t2q_bf, woffaw + (size_t)i * 192 * 256,
                                                       bOA + i * 192, offaw, nullptr, 192);
        sample_kernel<<<MT * NHH * 8 / 256, 256, 0, stream>>>(value01, 256, offaw, refp, 1, samp_bf);
        mgemm<2><<<dim3(MT / 64, 4), 256, 0, stream>>>(samp_bf, wout + (size_t)i * 65536,
                                                       out_b + i * CC, tgt, nullptr, 256);
        ln_kernel<<<MT / 4, 256, 0, stream>>>(tgt, ln2_g + i * CC, ln2_b + i * CC, nullptr, 0, t2q_bf);
        mgemm<1><<<dim3(MT / 64, 4), 256, 0, stream>>>(t2q_bf, wf1 + (size_t)i * 65536,
                                                       f1_b + i * FFND, nullptr, hbuf_bf, 256);
        mgemm<3><<<dim3(MT / 64, 4), 256, 0, stream>>>(hbuf_bf, wf2 + (size_t)i * 65536,
                                                       f2_b + i * CC, tgt, nullptr, 256);
    }
}